// Round 6
// baseline (1402.097 us; speedup 1.0000x reference)
//
#include <hip/hip_runtime.h>
#include <hip/hip_bf16.h>

#define M_DIM 8192      // B*S = 4*2048
#define K_DIM 4096
#define N_DIM 16384

#define BK 64
#define NT (K_DIM / BK)   // 64 K-tiles

typedef __attribute__((ext_vector_type(8))) short bf16x8;
typedef __attribute__((ext_vector_type(4))) float f32x4;
typedef __attribute__((ext_vector_type(4))) unsigned short u16x4;

__device__ __forceinline__ unsigned short f2bf(float f) {
  unsigned int u = __builtin_bit_cast(unsigned int, f);
  u += 0x7fffu + ((u >> 16) & 1u);     // RNE
  return (unsigned short)(u >> 16);
}

// fp32 -> bf16, 4 elements/thread/iter, grid-stride.
__global__ void cvt_kernel(const float* __restrict__ src,
                           unsigned short* __restrict__ dst, int n4) {
  int i = blockIdx.x * blockDim.x + threadIdx.x;
  int stride = gridDim.x * blockDim.x;
  for (; i < n4; i += stride) {
    f32x4 v = __builtin_nontemporal_load(&((const f32x4*)src)[i]);
    u16x4 o;
    o.x = f2bf(v.x); o.y = f2bf(v.y); o.z = f2bf(v.z); o.w = f2bf(v.w);
    ((u16x4*)dst)[i] = o;
  }
}

__device__ __forceinline__ void gload_lds16(const void* g, void* lds) {
  __builtin_amdgcn_global_load_lds(
      (const __attribute__((address_space(1))) unsigned int*)g,
      (__attribute__((address_space(3))) unsigned int*)lds, 16, 0, 0);
}

// ============================================================================
// PERSISTENT 256-block, 256x256 tile, BK=64, 8 waves. ROUND 6: collapsed
// K-tile to ONE 64-MFMA run + 2 barriers (was 8 phases / 8 barriers; ~270cyc
// overhead per phase was the measured 48% stall).
// Per K-tile u (par = u&1):
//   [24 ds_read_b128: af[8][2] from lA[par], bfr[4][2] from lB[par]]
//   [stage A(u+1) -> lA[par^1]]          (slots sealed by bar-B of tile u-1)
//   [setprio(1); 64 MFMA kk-outer; setprio(0)]  (compiler-counted lgkm)
//   barrier (bar-A: all waves consumed tile-u fragments)
//   [stage B(u+2) -> lB[par]]            (safe: after bar-A)
//   vmcnt(4)  (invariant: leaves exactly B(u+2)'s 4 gloads outstanding;
//              u==NT-2 -> vmcnt(0), u==NT-1 -> none)
//   barrier (bar-B: tile boundary)
// Sweep boundary (persistent r-loop): tile NT-1's bar-B seals all slots;
// then next sweep's 12 prologue gloads are issued BEFORE the 32 epilogue
// stores, so sweep-top vmcnt(4) retires [12 gloads + 28 stores] and leaves
// B(1)'s 4 gloads -> same invariant as steady state.
// LDS: lA 64KB | lB 64KB | epilogue bounce 32KB (wave-private 4KB, XOR-
// swizzled: phys col = (col + 4*row) & 63 -> write 2-way, read at b128 floor).
// Fragment swizzle unchanged: phys 8-elem block = logical ^ (row&7), staged
// via inverse-swizzled GLOBAL source + linear LDS dest (rule #21).
// ============================================================================
__global__ __launch_bounds__(512, 2) void gemm8p(const short* __restrict__ A,
                                                 const short* __restrict__ Bm,
                                                 const float* __restrict__ bias,
                                                 float* __restrict__ C) {
  extern __shared__ short lds[];
  short* lA = lds;                     // 4 half-slots * 8192 shorts
  short* lB = lds + 32768;             // 4 half-slots * 8192 shorts
  float* ep = (float*)(lds + 65536);   // 32 KB bounce

  const int tid = threadIdx.x;
  const int w = tid >> 6, l = tid & 63;
  const int wr = w >> 2;     // 0..1  (M half)
  const int wc = w & 3;      // 0..3  (N quarter)
  const int fr = l & 15;     // fragment row/col
  const int kq = l >> 4;     // k quarter
  const int sr = l >> 3;     // staging row-in-8
  const int sb = (l & 7) ^ sr;  // inverse-swizzled source block

  // ---- persistent tile assignment: fixed bm per block, bn sweeps 8 ----
  const int p = blockIdx.x;          // 0..255
  const int xcd = p & 7;
  const int slot = p >> 3;           // 0..31
  const int bm = xcd * 4 + (slot >> 3);  // 0..31 (A panel pinned per CU)
  const int bni = slot & 7;
  const size_t m0 = (size_t)bm * 256;
  const short* Abase = A + m0 * K_DIM;
  float* epw = ep + w * 1024;        // wave-private 4 KB

  // stage one half-tile (128 rows x 64 elems) = 2 x gload_lds16 per thread
  auto stage = [&](short* lbase, const short* gbase, int slotn, int half, int v) {
    const short* src = gbase + (size_t)(half * 128 + w * 8 + sr) * K_DIM +
                       (size_t)v * BK + sb * 8;
    short* dst = lbase + slotn * 8192 + w * 512;
    gload_lds16(src, dst);                          // rows 0..63 of half
    gload_lds16(src + (size_t)64 * K_DIM, dst + 4096);  // rows 64..127
  };

#pragma unroll 1
  for (int r = 0; r < 8; ++r) {
    const int bn = r * 8 + bni;        // 0..63
    const size_t n0 = (size_t)bn * 256;
    const short* Bbase = Bm + n0 * K_DIM;

    f32x4 acc[8][4];
#pragma unroll
    for (int mi = 0; mi < 8; ++mi)
#pragma unroll
      for (int ni = 0; ni < 4; ++ni) acc[mi][ni] = (f32x4){0.f, 0.f, 0.f, 0.f};

    if (r == 0) {
      // cold prologue: B(0)->lB[0,1], A(0)->lA[0,1], B(1)->lB[2,3]
      stage(lB, Bbase, 0, 0, 0);
      stage(lB, Bbase, 1, 1, 0);
      stage(lA, Abase, 0, 0, 0);
      stage(lA, Abase, 1, 1, 0);
      stage(lB, Bbase, 2, 0, 1);
      stage(lB, Bbase, 3, 1, 1);
    }
    // sweep top: retire everything except newest 4 gloads (= B(1)h1 pair+...)
    // cold: [12 g] -> retire 8 (B0,A0). warm: [12 g, 32 st] -> retire all
    // stores + 8 oldest gloads. Both leave B(1)'s 4 gloads outstanding.
    asm volatile("s_waitcnt vmcnt(4)");
    __builtin_amdgcn_s_barrier();
    __builtin_amdgcn_sched_barrier(0);

    // ---- one K-tile: 24 reads | stage A | 64 MFMA | bar | stage B |
    //      vmcnt | bar ----
    auto tile = [&](const int par, const int u) {
      bf16x8 af[8][2], bfr[4][2];
#pragma unroll
      for (int mi = 0; mi < 8; ++mi) {
        int row = mi * 16 + fr;
        int base = (par * 2 + wr) * 8192 + row * 64;
        int x7 = (row & 7) << 3;
        af[mi][0] = *(const bf16x8*)&lA[base + ((kq * 8) ^ x7)];
        af[mi][1] = *(const bf16x8*)&lA[base + ((32 + kq * 8) ^ x7)];
      }
#pragma unroll
      for (int ni = 0; ni < 4; ++ni) {
        int row = (wc & 1) * 64 + ni * 16 + fr;
        int base = (par * 2 + (wc >> 1)) * 8192 + row * 64;
        int x7 = (row & 7) << 3;
        bfr[ni][0] = *(const bf16x8*)&lB[base + ((kq * 8) ^ x7)];
        bfr[ni][1] = *(const bf16x8*)&lB[base + ((32 + kq * 8) ^ x7)];
      }
      if (u + 1 < NT) {
        stage(lA, Abase, ((par ^ 1) << 1) + 0, 0, u + 1);
        stage(lA, Abase, ((par ^ 1) << 1) + 1, 1, u + 1);
      }
      __builtin_amdgcn_s_setprio(1);
#pragma unroll
      for (int kk = 0; kk < 2; ++kk)
#pragma unroll
        for (int mi = 0; mi < 8; ++mi)
#pragma unroll
          for (int ni = 0; ni < 4; ++ni)
            acc[mi][ni] = __builtin_amdgcn_mfma_f32_16x16x32_bf16(
                af[mi][kk], bfr[ni][kk], acc[mi][ni], 0, 0, 0);
      __builtin_amdgcn_s_setprio(0);
      __builtin_amdgcn_s_barrier();   // bar-A: all waves consumed frags
      if (u + 2 < NT) {
        stage(lB, Bbase, (par << 1) + 0, 0, u + 2);
        stage(lB, Bbase, (par << 1) + 1, 1, u + 2);
      }
      __builtin_amdgcn_sched_barrier(0);
      if (u < NT - 2) {
        asm volatile("s_waitcnt vmcnt(4)");   // retire A(u+1),B(u+1)
      } else if (u == NT - 2) {
        asm volatile("s_waitcnt vmcnt(0)");   // drain for last tile
      }
      __builtin_amdgcn_sched_barrier(0);
      __builtin_amdgcn_s_barrier();   // bar-B: tile boundary
    };

    for (int t = 0; t < NT; t += 2) {
      tile(0, t);
      tile(1, t + 1);
    }

    // ---- next sweep's prologue gloads BEFORE epilogue stores ----
    if (r + 1 < 8) {
      const short* Bb2 = Bm + (size_t)(bn + 8) * 256 * K_DIM;
      stage(lB, Bb2, 0, 0, 0);
      stage(lB, Bb2, 1, 1, 0);
      stage(lA, Abase, 0, 0, 0);
      stage(lA, Abase, 1, 1, 0);
      stage(lB, Bb2, 2, 0, 1);
      stage(lB, Bb2, 3, 1, 1);
    }

    // ---- epilogue: XOR-swizzled LDS bounce -> 256B-segment nt stores ----
    f32x4 bias4 = *(const f32x4*)&bias[n0 + wc * 64 + fr * 4];
#pragma unroll
    for (int mi = 0; mi < 8; ++mi) {
#pragma unroll
      for (int ni = 0; ni < 4; ++ni)
#pragma unroll
        for (int j = 0; j < 4; ++j) {
          int row = kq * 4 + j;
          epw[row * 64 + ((ni * 16 + fr + 4 * row) & 63)] = acc[mi][ni][j];
        }
#pragma unroll
      for (int ps = 0; ps < 4; ++ps) {
        int row = ps * 4 + kq;
        f32x4 v = *(const f32x4*)&epw[row * 64 + ((fr * 4 + 4 * row) & 63)];
        v += bias4;
        size_t grow = m0 + (size_t)wr * 128 + mi * 16 + row;
        __builtin_nontemporal_store(
            v, (f32x4*)&C[grow * N_DIM + n0 + wc * 64 + fr * 4]);
      }
    }
  }
}

// ---- fallback (ws too small): 128^2 kernel, fp32 in, reg-staged ----
__global__ __launch_bounds__(256) void gemm_f32(const float* __restrict__ Af,
                                                const float* __restrict__ Bf,
                                                const float* __restrict__ bias,
                                                float* __restrict__ C) {
  __shared__ short lA[128 * 64];
  __shared__ short lB[128 * 64];
  const int tid = threadIdx.x;
  const int w = tid >> 6, l = tid & 63;
  const int wr = w >> 1, wc = w & 1;
  int bid = blockIdx.x;
  int cpx = (M_DIM / 128) * (N_DIM / 128) / 8;
  int swz = (bid & 7) * cpx + (bid >> 3);
  const int bm = swz / (N_DIM / 128);
  const int bn = swz % (N_DIM / 128);
  const size_t m0 = (size_t)bm * 128, n0 = (size_t)bn * 128;
  const int lr = l >> 3, fr = l & 15, kq = l >> 4;

  f32x4 acc[4][4];
#pragma unroll
  for (int mi = 0; mi < 4; ++mi)
#pragma unroll
    for (int ni = 0; ni < 4; ++ni) acc[mi][ni] = (f32x4){0.f, 0.f, 0.f, 0.f};
  float bv[4];
#pragma unroll
  for (int ni = 0; ni < 4; ++ni) bv[ni] = bias[n0 + 64 * wc + 16 * ni + fr];

  for (int kt = 0; kt < K_DIM; kt += 64) {
    const float* Ab = Af + m0 * K_DIM + kt;
    const float* Bb = Bf + n0 * K_DIM + kt;
#pragma unroll
    for (int i = 0; i < 4; ++i) {
      int row = 32 * i + 8 * w + lr;
      int dsoff = row * 64 + ((8 * (l & 7)) ^ (lr << 3));
      f32x4 a0 = *(const f32x4*)(Ab + (size_t)row * K_DIM + 8 * (l & 7));
      f32x4 a1 = *(const f32x4*)(Ab + (size_t)row * K_DIM + 8 * (l & 7) + 4);
      bf16x8 ra;
#pragma unroll
      for (int j = 0; j < 4; ++j) { ra[j] = (short)f2bf(a0[j]); ra[j + 4] = (short)f2bf(a1[j]); }
      *(bf16x8*)&lA[dsoff] = ra;
      f32x4 b0 = *(const f32x4*)(Bb + (size_t)row * K_DIM + 8 * (l & 7));
      f32x4 b1 = *(const f32x4*)(Bb + (size_t)row * K_DIM + 8 * (l & 7) + 4);
      bf16x8 rb;
#pragma unroll
      for (int j = 0; j < 4; ++j) { rb[j] = (short)f2bf(b0[j]); rb[j + 4] = (short)f2bf(b1[j]); }
      *(bf16x8*)&lB[dsoff] = rb;
    }
    __syncthreads();
#pragma unroll
    for (int kk = 0; kk < 64; kk += 32) {
      bf16x8 af[4], bf_[4];
#pragma unroll
      for (int mi = 0; mi < 4; ++mi)
        af[mi] = *(const bf16x8*)&lA[(64 * wr + 16 * mi + fr) * 64 +
                                     ((kk + 8 * kq) ^ ((fr & 7) << 3))];
#pragma unroll
      for (int ni = 0; ni < 4; ++ni)
        bf_[ni] = *(const bf16x8*)&lB[(64 * wc + 16 * ni + fr) * 64 +
                                      ((kk + 8 * kq) ^ ((fr & 7) << 3))];
#pragma unroll
      for (int mi = 0; mi < 4; ++mi)
#pragma unroll
        for (int ni = 0; ni < 4; ++ni)
          acc[mi][ni] = __builtin_amdgcn_mfma_f32_16x16x32_bf16(
              af[mi], bf_[ni], acc[mi][ni], 0, 0, 0);
    }
    __syncthreads();
  }
  const int crow0 = kq * 4;
#pragma unroll
  for (int mi = 0; mi < 4; ++mi)
#pragma unroll
    for (int ni = 0; ni < 4; ++ni) {
      f32x4 v = acc[mi][ni];
      size_t col = n0 + 64 * wc + 16 * ni + fr;
      size_t rb = m0 + 64 * wr + 16 * mi + crow0;
#pragma unroll
      for (int j = 0; j < 4; ++j) C[(rb + j) * N_DIM + col] = v[j] + bv[ni];
    }
}

extern "C" void kernel_launch(void* const* d_in, const int* in_sizes, int n_in,
                              void* d_out, int out_size, void* d_ws, size_t ws_size,
                              hipStream_t stream) {
  const float* x = (const float*)d_in[0];     // [8192][4096]
  const float* W = (const float*)d_in[1];     // [16384][4096]
  const float* bias = (const float*)d_in[2];  // [16384]
  float* out = (float*)d_out;

  const size_t nA = (size_t)M_DIM * K_DIM;
  const size_t nB = (size_t)N_DIM * K_DIM;
  const size_t need = (nA + nB) * sizeof(unsigned short);  // 192 MB

  if (ws_size >= need) {
    unsigned short* wsA = (unsigned short*)d_ws;
    unsigned short* wsB = wsA + nA;
    hipFuncSetAttribute((const void*)gemm8p,
                        hipFuncAttributeMaxDynamicSharedMemorySize, 163840);
    cvt_kernel<<<4096, 256, 0, stream>>>(x, wsA, (int)(nA / 4));
    cvt_kernel<<<4096, 256, 0, stream>>>(W, wsB, (int)(nB / 4));
    gemm8p<<<256, 512, 163840, stream>>>((const short*)wsA, (const short*)wsB,
                                         bias, out);
  } else {
    const int nblk = (M_DIM / 128) * (N_DIM / 128);  // 8192
    gemm_f32<<<nblk, 256, 0, stream>>>(x, W, bias, out);
  }
}

// Round 8
// 1001.116 us; speedup vs baseline: 1.4005x; 1.4005x over previous
//
#include <hip/hip_runtime.h>
#include <hip/hip_bf16.h>

#define M_DIM 8192      // B*S = 4*2048
#define K_DIM 4096
#define N_DIM 16384

#define BK 64
#define NT (K_DIM / BK)   // 64 K-tiles

typedef __attribute__((ext_vector_type(8))) short bf16x8;
typedef __attribute__((ext_vector_type(4))) float f32x4;
typedef __attribute__((ext_vector_type(4))) unsigned short u16x4;

__device__ __forceinline__ unsigned short f2bf(float f) {
  unsigned int u = __builtin_bit_cast(unsigned int, f);
  u += 0x7fffu + ((u >> 16) & 1u);     // RNE
  return (unsigned short)(u >> 16);
}

__global__ void cvt_kernel(const float* __restrict__ src,
                           unsigned short* __restrict__ dst, int n4) {
  int i = blockIdx.x * blockDim.x + threadIdx.x;
  int stride = gridDim.x * blockDim.x;
  for (; i < n4; i += stride) {
    f32x4 v = __builtin_nontemporal_load(&((const f32x4*)src)[i]);
    u16x4 o;
    o.x = f2bf(v.x); o.y = f2bf(v.y); o.z = f2bf(v.z); o.w = f2bf(v.w);
    ((u16x4*)dst)[i] = o;
  }
}

__device__ __forceinline__ void gload_lds16(const void* g, void* lds) {
  __builtin_amdgcn_global_load_lds(
      (const __attribute__((address_space(1))) unsigned int*)g,
      (__attribute__((address_space(3))) unsigned int*)lds, 16, 0, 0);
}

// ============================================================================
// PERSISTENT 256-block, 256x256 tile, BK=64, 8 waves (2M x 4N). ROUND 8:
// read/MFMA INTERLEAVE with 2 barriers/tile and reorder/spill-ROBUST waits.
// Per tile u (par=u&1, parN=par^1):
//  p0: stage A(u+1)->lA[parN] (dead: last read tile u-1, sealed at its
//      boundary); read bfc[8] (B frags) THEN af0,af1 (order pinned by
//      sched_barrier); lgkmcnt(4):"memory" (own 8 B-reads done); s_barrier
//      -> ALL waves' B(u) reads done.
//  body (no barriers): stage B(u+2)h0 -> lB[par] (B(u) regs-safe after p0
//      barrier); { mfmaG(g,kk) || rdA(g+2) } x8 interleaved -> LDS pipe
//      busy while MFMA pipe busy; stage B(u+2)h1 mid-body.
//  boundary: lgkmcnt(0):"memory" (all my lA[par]/lB[par] reads drained ->
//      slots safe for tile u+1's stages); vmcnt(0):"memory" (A(u+1),B(u+1),
//      B(u+2) landed -- issued >=1 tile ago, drain ~free; ALWAYS correct
//      regardless of compiler reordering or scratch traffic); s_barrier.
// Invariant entering tile u: A(u),B(u),B(u+1) landed (vmcnt(0) boundary).
// Tail: u=NT-2 stages A only; u=NT-1 stages nothing.
// Sweep boundary: stages for next sweep (12 gl) BEFORE epilogue stores;
// sweep-top vmcnt(0)+barrier drains everything.
// LDS: lA 4x8192 | lB 4x8192 | ep 32KB bounce (wave-private 4KB, swizzled).
// Fragment swizzle: phys 16B block = logical ^ (row&7); linear LDS dest +
// inverse-swizzled GLOBAL source (rule #21). Verified r2-r6.
// ============================================================================
__global__ __launch_bounds__(512, 2) void gemm8p(const short* __restrict__ A,
                                                 const short* __restrict__ Bm,
                                                 const float* __restrict__ bias,
                                                 float* __restrict__ C) {
  extern __shared__ short lds[];
  short* lA = lds;                     // 4 half-slots * 8192 shorts
  short* lB = lds + 32768;             // 4 half-slots * 8192 shorts
  float* ep = (float*)(lds + 65536);   // 32 KB bounce

  const int tid = threadIdx.x;
  const int w = tid >> 6, l = tid & 63;
  const int wr = w >> 2;     // 0..1  (M half)
  const int wc = w & 3;      // 0..3  (N quarter)
  const int fr = l & 15;     // fragment row/col
  const int kq = l >> 4;     // k quarter
  const int sr = l >> 3;     // staging row-in-8
  const int sb = (l & 7) ^ sr;  // inverse-swizzled source block
  const int x7 = (fr & 7) << 3;

  // ---- persistent: fixed bm per block (A panel pinned), bn sweeps 8 ----
  const int p = blockIdx.x;          // 0..255
  const int xcd = p & 7;
  const int slot = p >> 3;           // 0..31
  const int bm = xcd * 4 + (slot >> 3);
  const int bni = slot & 7;
  const size_t m0 = (size_t)bm * 256;
  const short* Abase = A + m0 * K_DIM;
  float* epw = ep + w * 1024;        // wave-private 4 KB

  auto stage = [&](short* lbase, const short* gbase, int slotn, int half, int v) {
    const short* src = gbase + (size_t)(half * 128 + w * 8 + sr) * K_DIM +
                       (size_t)v * BK + sb * 8;
    short* dst = lbase + slotn * 8192 + w * 512;
    gload_lds16(src, dst);
    gload_lds16(src + (size_t)64 * K_DIM, dst + 4096);
  };

#pragma unroll 1
  for (int r = 0; r < 8; ++r) {
    const int bn = r * 8 + bni;
    const size_t n0 = (size_t)bn * 256;
    const short* Bbase = Bm + n0 * K_DIM;

    f32x4 acc[8][4];
#pragma unroll
    for (int mi = 0; mi < 8; ++mi)
#pragma unroll
      for (int ni = 0; ni < 4; ++ni) acc[mi][ni] = (f32x4){0.f, 0.f, 0.f, 0.f};

    bf16x8 bfc[8], af0[2], af1[2], af2[2], af3[2];

    auto rdA = [&](bf16x8* d, int par, int g, int kk) {
      const int base = (par * 2 + wr) * 8192;
      const int off = (kk * 32 + kq * 8) ^ x7;
      d[0] = *(const bf16x8*)&lA[base + (g * 32 + fr) * 64 + off];
      d[1] = *(const bf16x8*)&lA[base + (g * 32 + 16 + fr) * 64 + off];
    };
    auto rdB = [&](bf16x8* d, int par, int kk) {
      const int base = (par * 2 + (wc >> 1)) * 8192 + ((wc & 1) * 64 + fr) * 64;
      const int off = (kk * 32 + kq * 8) ^ x7;
#pragma unroll
      for (int ni = 0; ni < 4; ++ni)
        d[ni] = *(const bf16x8*)&lB[base + ni * 1024 + off];
    };
    auto mfmaG = [&](const bf16x8* a, int g, int kk) {
      __builtin_amdgcn_s_setprio(1);
#pragma unroll
      for (int i = 0; i < 2; ++i)
#pragma unroll
        for (int ni = 0; ni < 4; ++ni)
          acc[g * 2 + i][ni] = __builtin_amdgcn_mfma_f32_16x16x32_bf16(
              a[i], bfc[kk * 4 + ni], acc[g * 2 + i][ni], 0, 0, 0);
      __builtin_amdgcn_s_setprio(0);
    };

    if (r == 0) {
      // cold prologue: B(0)->lB[0,1], A(0)->lA[0,1], B(1)->lB[2,3]
      stage(lB, Bbase, 0, 0, 0);
      stage(lB, Bbase, 1, 1, 0);
      stage(lA, Abase, 0, 0, 0);
      stage(lA, Abase, 1, 1, 0);
      stage(lB, Bbase, 2, 0, 1);
      stage(lB, Bbase, 3, 1, 1);
    }
    // sweep top: full drain (robust; cost ~= once per sweep)
    asm volatile("s_waitcnt vmcnt(0)" ::: "memory");
    __builtin_amdgcn_s_barrier();
    __builtin_amdgcn_sched_barrier(0);

    auto tile = [&](const int par, const int u) {
      const int parN = par ^ 1;
      // ---- p0 ----
      if (u + 1 < NT) {
        stage(lA, Abase, (parN << 1) + 0, 0, u + 1);
        stage(lA, Abase, (parN << 1) + 1, 1, u + 1);
      }
      rdB(bfc, par, 0);
      rdB(bfc + 4, par, 1);
      __builtin_amdgcn_sched_barrier(0);   // pin: B reads before A reads
      rdA(af0, par, 0, 0);
      rdA(af1, par, 1, 0);
      __builtin_amdgcn_sched_barrier(0);
      asm volatile("s_waitcnt lgkmcnt(4)" ::: "memory");  // own B reads done
      __builtin_amdgcn_s_barrier();        // all waves' B(u) reads done
      // ---- interleaved body (no barriers) ----
      if (u + 2 < NT) stage(lB, Bbase, (par << 1) + 0, 0, u + 2);
      mfmaG(af0, 0, 0);  rdA(af2, par, 2, 0);
      mfmaG(af1, 1, 0);  rdA(af3, par, 3, 0);
      if (u + 2 < NT) stage(lB, Bbase, (par << 1) + 1, 1, u + 2);
      mfmaG(af2, 2, 0);  rdA(af0, par, 0, 1);
      mfmaG(af3, 3, 0);  rdA(af1, par, 1, 1);
      mfmaG(af0, 0, 1);  rdA(af2, par, 2, 1);
      mfmaG(af1, 1, 1);  rdA(af3, par, 3, 1);
      mfmaG(af2, 2, 1);
      mfmaG(af3, 3, 1);
      // ---- boundary ----
      __builtin_amdgcn_sched_barrier(0);
      asm volatile("s_waitcnt lgkmcnt(0)" ::: "memory");  // my LDS reads done
      asm volatile("s_waitcnt vmcnt(0)" ::: "memory");    // prefetch landed
      __builtin_amdgcn_sched_barrier(0);
      __builtin_amdgcn_s_barrier();
    };

#pragma unroll 1
    for (int t = 0; t < NT; t += 2) {
      tile(0, t);
      tile(1, t + 1);
    }

    // ---- next sweep's prologue gloads BEFORE epilogue stores ----
    if (r + 1 < 8) {
      const short* Bb2 = Bm + (size_t)(bn + 8) * 256 * K_DIM;
      stage(lB, Bb2, 0, 0, 0);
      stage(lB, Bb2, 1, 1, 0);
      stage(lA, Abase, 0, 0, 0);
      stage(lA, Abase, 1, 1, 0);
      stage(lB, Bb2, 2, 0, 1);
      stage(lB, Bb2, 3, 1, 1);
    }

    // ---- epilogue: XOR-swizzled LDS bounce -> 256B-segment nt stores ----
    f32x4 bias4 = *(const f32x4*)&bias[n0 + wc * 64 + fr * 4];
#pragma unroll
    for (int mi = 0; mi < 8; ++mi) {
#pragma unroll
      for (int ni = 0; ni < 4; ++ni)
#pragma unroll
        for (int j = 0; j < 4; ++j) {
          int row = kq * 4 + j;
          epw[row * 64 + ((ni * 16 + fr + 4 * row) & 63)] = acc[mi][ni][j];
        }
#pragma unroll
      for (int ps = 0; ps < 4; ++ps) {
        int row = ps * 4 + kq;
        f32x4 v = *(const f32x4*)&epw[row * 64 + ((fr * 4 + 4 * row) & 63)];
        v += bias4;
        size_t grow = m0 + (size_t)wr * 128 + mi * 16 + row;
        __builtin_nontemporal_store(
            v, (f32x4*)&C[grow * N_DIM + n0 + wc * 64 + fr * 4]);
      }
    }
  }
}

// ---- fallback (ws too small): 128^2 kernel, fp32 in, reg-staged ----
__global__ __launch_bounds__(256) void gemm_f32(const float* __restrict__ Af,
                                                const float* __restrict__ Bf,
                                                const float* __restrict__ bias,
                                                float* __restrict__ C) {
  __shared__ short lA[128 * 64];
  __shared__ short lB[128 * 64];
  const int tid = threadIdx.x;
  const int w = tid >> 6, l = tid & 63;
  const int wr = w >> 1, wc = w & 1;
  int bid = blockIdx.x;
  int cpx = (M_DIM / 128) * (N_DIM / 128) / 8;
  int swz = (bid & 7) * cpx + (bid >> 3);
  const int bm = swz / (N_DIM / 128);
  const int bn = swz % (N_DIM / 128);
  const size_t m0 = (size_t)bm * 128, n0 = (size_t)bn * 128;
  const int lr = l >> 3, fr = l & 15, kq = l >> 4;

  f32x4 acc[4][4];
#pragma unroll
  for (int mi = 0; mi < 4; ++mi)
#pragma unroll
    for (int ni = 0; ni < 4; ++ni) acc[mi][ni] = (f32x4){0.f, 0.f, 0.f, 0.f};
  float bv[4];
#pragma unroll
  for (int ni = 0; ni < 4; ++ni) bv[ni] = bias[n0 + 64 * wc + 16 * ni + fr];

  for (int kt = 0; kt < K_DIM; kt += 64) {
    const float* Ab = Af + m0 * K_DIM + kt;
    const float* Bb = Bf + n0 * K_DIM + kt;
#pragma unroll
    for (int i = 0; i < 4; ++i) {
      int row = 32 * i + 8 * w + lr;
      int dsoff = row * 64 + ((8 * (l & 7)) ^ (lr << 3));
      f32x4 a0 = *(const f32x4*)(Ab + (size_t)row * K_DIM + 8 * (l & 7));
      f32x4 a1 = *(const f32x4*)(Ab + (size_t)row * K_DIM + 8 * (l & 7) + 4);
      bf16x8 ra;
#pragma unroll
      for (int j = 0; j < 4; ++j) { ra[j] = (short)f2bf(a0[j]); ra[j + 4] = (short)f2bf(a1[j]); }
      *(bf16x8*)&lA[dsoff] = ra;
      f32x4 b0 = *(const f32x4*)(Bb + (size_t)row * K_DIM + 8 * (l & 7));
      f32x4 b1 = *(const f32x4*)(Bb + (size_t)row * K_DIM + 8 * (l & 7) + 4);
      bf16x8 rb;
#pragma unroll
      for (int j = 0; j < 4; ++j) { rb[j] = (short)f2bf(b0[j]); rb[j + 4] = (short)f2bf(b1[j]); }
      *(bf16x8*)&lB[dsoff] = rb;
    }
    __syncthreads();
#pragma unroll
    for (int kk = 0; kk < 64; kk += 32) {
      bf16x8 af[4], bf_[4];
#pragma unroll
      for (int mi = 0; mi < 4; ++mi)
        af[mi] = *(const bf16x8*)&lA[(64 * wr + 16 * mi + fr) * 64 +
                                     ((kk + 8 * kq) ^ ((fr & 7) << 3))];
#pragma unroll
      for (int ni = 0; ni < 4; ++ni)
        bf_[ni] = *(const bf16x8*)&lB[(64 * wc + 16 * ni + fr) * 64 +
                                      ((kk + 8 * kq) ^ ((fr & 7) << 3))];
#pragma unroll
      for (int mi = 0; mi < 4; ++mi)
#pragma unroll
        for (int ni = 0; ni < 4; ++ni)
          acc[mi][ni] = __builtin_amdgcn_mfma_f32_16x16x32_bf16(
              af[mi], bf_[ni], acc[mi][ni], 0, 0, 0);
    }
    __syncthreads();
  }
  const int crow0 = kq * 4;
#pragma unroll
  for (int mi = 0; mi < 4; ++mi)
#pragma unroll
    for (int ni = 0; ni < 4; ++ni) {
      f32x4 v = acc[mi][ni];
      size_t col = n0 + 64 * wc + 16 * ni + fr;
      size_t rb = m0 + 64 * wr + 16 * mi + crow0;
#pragma unroll
      for (int j = 0; j < 4; ++j) C[(rb + j) * N_DIM + col] = v[j] + bv[ni];
    }
}

extern "C" void kernel_launch(void* const* d_in, const int* in_sizes, int n_in,
                              void* d_out, int out_size, void* d_ws, size_t ws_size,
                              hipStream_t stream) {
  const float* x = (const float*)d_in[0];     // [8192][4096]
  const float* W = (const float*)d_in[1];     // [16384][4096]
  const float* bias = (const float*)d_in[2];  // [16384]
  float* out = (float*)d_out;

  const size_t nA = (size_t)M_DIM * K_DIM;
  const size_t nB = (size_t)N_DIM * K_DIM;
  const size_t need = (nA + nB) * sizeof(unsigned short);  // 192 MB

  if (ws_size >= need) {
    unsigned short* wsA = (unsigned short*)d_ws;
    unsigned short* wsB = wsA + nA;
    hipFuncSetAttribute((const void*)gemm8p,
                        hipFuncAttributeMaxDynamicSharedMemorySize, 163840);
    cvt_kernel<<<4096, 256, 0, stream>>>(x, wsA, (int)(nA / 4));
    cvt_kernel<<<4096, 256, 0, stream>>>(W, wsB, (int)(nB / 4));
    gemm8p<<<256, 512, 163840, stream>>>((const short*)wsA, (const short*)wsB,
                                         bias, out);
  } else {
    const int nblk = (M_DIM / 128) * (N_DIM / 128);  // 8192
    gemm_f32<<<nblk, 256, 0, stream>>>(x, W, bias, out);
  }
}